// Round 3
// baseline (173.644 us; speedup 1.0000x reference)
//
#include <hip/hip_runtime.h>
#include <hip/hip_bf16.h>

#define C_DIM 8192
#define E_DIM 512

using f32x4 = __attribute__((ext_vector_type(4))) float;
using s16x8 = __attribute__((ext_vector_type(8))) short;

__device__ inline void gload_lds16(const void* g, void* l) {
  __builtin_amdgcn_global_load_lds(
      (const __attribute__((address_space(1))) unsigned*)g,
      (__attribute__((address_space(3))) unsigned*)l, 16, 0, 0);
}

__device__ inline unsigned pack_bf16(float a, float b) {
  unsigned ua = __float_as_uint(a), ub = __float_as_uint(b);
  ua = (ua + 0x7fffu + ((ua >> 16) & 1u)) >> 16;
  ub = (ub + 0x7fffu + ((ub >> 16) & 1u)) >> 16;
  return ua | (ub << 16);
}

__device__ inline float bf2f(unsigned short u) {
  return __uint_as_float(((unsigned)u) << 16);
}

// ---------------- Kernel 1: row L2 normalize -> bf16 only -------------------
__global__ __launch_bounds__(256) void norm_kernel(
    const float* __restrict__ P, unsigned* __restrict__ Pb) {
  int wid = threadIdx.x >> 6, lane = threadIdx.x & 63;
  int row = blockIdx.x * 4 + wid;
  const float4* src = (const float4*)(P + (size_t)row * E_DIM);
  float4 v0 = src[lane], v1 = src[lane + 64];
  float ss = v0.x * v0.x + v0.y * v0.y + v0.z * v0.z + v0.w * v0.w +
             v1.x * v1.x + v1.y * v1.y + v1.z * v1.z + v1.w * v1.w;
  for (int m = 32; m; m >>= 1) ss += __shfl_xor(ss, m);
  float inv = 1.0f / fmaxf(sqrtf(ss), 1e-12f);
  v0.x *= inv; v0.y *= inv; v0.z *= inv; v0.w *= inv;
  v1.x *= inv; v1.y *= inv; v1.z *= inv; v1.w *= inv;
  uint2* bd = (uint2*)(Pb + (size_t)row * (E_DIM / 2));
  uint2 b0, b1;
  b0.x = pack_bf16(v0.x, v0.y); b0.y = pack_bf16(v0.z, v0.w);
  b1.x = pack_bf16(v1.x, v1.y); b1.y = pack_bf16(v1.z, v1.w);
  bd[lane] = b0; bd[lane + 64] = b1;
}

// ---------------- Kernel 2: q = column sums of Pb (bf16) --------------------
// Each wave reads full 1KB rows coalesced; lane owns cols [lane*8, lane*8+8).
__global__ __launch_bounds__(256) void qsum_kernel(
    const unsigned short* __restrict__ Pb, float* __restrict__ q) {
  __shared__ float red[4][512];
  int wid = threadIdx.x >> 6, lane = threadIdx.x & 63;
  float a[8];
#pragma unroll
  for (int k = 0; k < 8; ++k) a[k] = 0.f;
  for (int i = 0; i < 32; ++i) {
    int row = blockIdx.x * 128 + wid * 32 + i;
    uint4 v = *(const uint4*)(Pb + (size_t)row * E_DIM + lane * 8);
    a[0] += bf2f((unsigned short)(v.x & 0xffff));
    a[1] += bf2f((unsigned short)(v.x >> 16));
    a[2] += bf2f((unsigned short)(v.y & 0xffff));
    a[3] += bf2f((unsigned short)(v.y >> 16));
    a[4] += bf2f((unsigned short)(v.z & 0xffff));
    a[5] += bf2f((unsigned short)(v.z >> 16));
    a[6] += bf2f((unsigned short)(v.w & 0xffff));
    a[7] += bf2f((unsigned short)(v.w >> 16));
  }
#pragma unroll
  for (int k = 0; k < 8; ++k) red[wid][lane * 8 + k] = a[k];
  __syncthreads();
  for (int c = threadIdx.x; c < 512; c += 256) {
    float t = red[0][c] + red[1][c] + red[2][c] + red[3][c];
    atomicAdd(&q[c], t);
  }
}

// ---------------- Kernel 3: s_j = dot(Pb[j], q) -----------------------------
__global__ __launch_bounds__(256) void ssum_kernel(
    const unsigned short* __restrict__ Pb, const float* __restrict__ q,
    float* __restrict__ s) {
  int wid = threadIdx.x >> 6, lane = threadIdx.x & 63;
  int row = blockIdx.x * 4 + wid;
  uint4 v = *(const uint4*)(Pb + (size_t)row * E_DIM + lane * 8);
  const float4* qv = (const float4*)q;
  float4 q0 = qv[lane * 2], q1 = qv[lane * 2 + 1];
  float d = bf2f((unsigned short)(v.x & 0xffff)) * q0.x +
            bf2f((unsigned short)(v.x >> 16)) * q0.y +
            bf2f((unsigned short)(v.y & 0xffff)) * q0.z +
            bf2f((unsigned short)(v.y >> 16)) * q0.w +
            bf2f((unsigned short)(v.z & 0xffff)) * q1.x +
            bf2f((unsigned short)(v.z >> 16)) * q1.y +
            bf2f((unsigned short)(v.w & 0xffff)) * q1.z +
            bf2f((unsigned short)(v.w >> 16)) * q1.w;
  for (int m = 32; m; m >>= 1) d += __shfl_xor(d, m);
  if (lane == 0) s[row] = d;
}

// ---------------- Kernel 4: fused Gram + exp-entropy partials ---------------
// Upper-triangle 128x128 tiles, symmetric mirror via column partials.
// 2-phase double-buffered pipeline: STAGE(next) issued BEFORE ds_read+MFMA of
// current, single __syncthreads (vmcnt drain) per K-step AFTER compute.
__global__ __launch_bounds__(256) void gram_kernel(
    const unsigned short* __restrict__ Pb, float* __restrict__ Z, float* __restrict__ S) {
  __shared__ unsigned short As[2 * 128 * 64];
  __shared__ unsigned short Bs[2 * 128 * 64];

  // XCD-aware remap (2080 = 8 * 260, bijective) then triangular decode
  int i0 = blockIdx.x;
  int i = (i0 & 7) * 260 + (i0 >> 3);
  float bi = 64.5f - sqrtf(64.5f * 64.5f - 2.0f * (float)i);
  int by = (int)bi;
  if (by < 0) by = 0;
  while (64 * (by + 1) - ((by + 1) * by) / 2 <= i) ++by;
  while (64 * by - (by * (by - 1)) / 2 > i) --by;
  int bx = by + (i - (64 * by - (by * (by - 1)) / 2));
  bool diag = (bx == by);

  int tid = threadIdx.x, wid = tid >> 6, lane = tid & 63;
  int wr = wid >> 1, wc = wid & 1;
  int l15 = lane & 15, lh = lane >> 4;

  f32x4 acc[4][4];
  for (int m = 0; m < 4; ++m)
    for (int n = 0; n < 4; ++n)
      acc[m][n] = (f32x4){0.f, 0.f, 0.f, 0.f};

  int rs = lane >> 3;                 // row within 8-row chunk
  int ksw = ((lane & 7) ^ rs) * 8;    // pre-swizzled col element (XOR involution)
  const unsigned short* arow = Pb + (size_t)(by * 128) * E_DIM;
  const unsigned short* brow = Pb + (size_t)(bx * 128) * E_DIM;

#define STAGE(buf, kt)                                                        \
  {                                                                           \
    _Pragma("unroll") for (int j = 0; j < 4; ++j) {                           \
      int ci = wid * 4 + j;                                                   \
      int r = ci * 8 + rs;                                                    \
      int k = (kt) * 64 + ksw;                                                \
      gload_lds16(arow + (size_t)r * E_DIM + k,                               \
                  (char*)As + (buf) * 16384 + ci * 1024);                     \
      gload_lds16(brow + (size_t)r * E_DIM + k,                               \
                  (char*)Bs + (buf) * 16384 + ci * 1024);                     \
    }                                                                         \
  }

  STAGE(0, 0);
  __syncthreads();

  int cur = 0;
#pragma unroll
  for (int kt = 0; kt < 8; ++kt) {
    if (kt < 7) STAGE(cur ^ 1, kt + 1);

    s16x8 af[4][2], bfr[4][2];
#pragma unroll
    for (int m = 0; m < 4; ++m)
#pragma unroll
      for (int kk = 0; kk < 2; ++kk) {
        int row = wr * 64 + m * 16 + l15;
        int slot = (kk * 4 + lh) ^ (l15 & 7);
        af[m][kk] = *(const s16x8*)(As + cur * 8192 + row * 64 + slot * 8);
      }
#pragma unroll
    for (int n = 0; n < 4; ++n)
#pragma unroll
      for (int kk = 0; kk < 2; ++kk) {
        int row = wc * 64 + n * 16 + l15;
        int slot = (kk * 4 + lh) ^ (l15 & 7);
        bfr[n][kk] = *(const s16x8*)(Bs + cur * 8192 + row * 64 + slot * 8);
      }

    __builtin_amdgcn_s_setprio(1);
#pragma unroll
    for (int kk = 0; kk < 2; ++kk)
#pragma unroll
      for (int m = 0; m < 4; ++m)
#pragma unroll
        for (int n = 0; n < 4; ++n)
          acc[m][n] = __builtin_amdgcn_mfma_f32_16x16x32_bf16(
              af[m][kk], bfr[n][kk], acc[m][n], 0, 0, 0);
    __builtin_amdgcn_s_setprio(0);

    if (kt < 7) {
      __syncthreads();  // vmcnt(0)+lgkmcnt(0) drain AFTER compute
      cur ^= 1;
    }
  }
#undef STAGE

  // epilogue: row partials (reduce over l15) + col partials (reduce over lh)
  int rowbase = by * 128 + wr * 64;
  int colbase = bx * 128 + wc * 64;
  float zc[4], sc[4];
#pragma unroll
  for (int n = 0; n < 4; ++n) { zc[n] = 0.f; sc[n] = 0.f; }

#pragma unroll
  for (int m = 0; m < 4; ++m) {
#pragma unroll
    for (int reg = 0; reg < 4; ++reg) {
      float z = 0.f, s = 0.f;
#pragma unroll
      for (int n = 0; n < 4; ++n) {
        float g = acc[m][n][reg];
        float e = __expf(g);
        z += e;
        s += e * g;
        zc[n] += e;
        sc[n] += e * g;
      }
      for (int msk = 8; msk; msk >>= 1) {
        z += __shfl_xor(z, msk);
        s += __shfl_xor(s, msk);
      }
      if (l15 == 0) {
        int grow = rowbase + m * 16 + lh * 4 + reg;
        atomicAdd(&Z[grow], z);
        atomicAdd(&S[grow], s);
      }
    }
  }
  if (!diag) {
#pragma unroll
    for (int n = 0; n < 4; ++n) {
      float z = zc[n], s = sc[n];
      z += __shfl_xor(z, 16); s += __shfl_xor(s, 16);
      z += __shfl_xor(z, 32); s += __shfl_xor(s, 32);
      if (lh == 0) {
        int gcol = colbase + n * 16 + l15;
        atomicAdd(&Z[gcol], z);
        atomicAdd(&S[gcol], s);
      }
    }
  }
}

// ---------------- Kernel 5: finalize ----------------------------------------
__device__ inline float bsum(float v, volatile float* red) {
  int lane = threadIdx.x & 63, wid = threadIdx.x >> 6;
  for (int k = 32; k; k >>= 1) v += __shfl_xor(v, k);
  __syncthreads();
  if (lane == 0) red[wid] = v;
  __syncthreads();
  float r = 0.f;
  if (wid == 0) {
    r = (lane < 16) ? red[lane] : 0.f;
    for (int k = 8; k; k >>= 1) r += __shfl_xor(r, k);
  }
  if (threadIdx.x == 0) red[16] = r;
  __syncthreads();
  return red[16];
}

__device__ inline float bmax(float v, volatile float* red) {
  int lane = threadIdx.x & 63, wid = threadIdx.x >> 6;
  for (int k = 32; k; k >>= 1) v = fmaxf(v, __shfl_xor(v, k));
  __syncthreads();
  if (lane == 0) red[wid] = v;
  __syncthreads();
  float r = -3.4e38f;
  if (wid == 0) {
    r = (lane < 16) ? red[lane] : -3.4e38f;
    for (int k = 8; k; k >>= 1) r = fmaxf(r, __shfl_xor(r, k));
  }
  if (threadIdx.x == 0) red[16] = r;
  __syncthreads();
  return red[16];
}

__global__ __launch_bounds__(1024) void final_kernel(
    const float* __restrict__ s, const float* __restrict__ Z,
    const float* __restrict__ S, float* __restrict__ out) {
  __shared__ float red[17];
  int tid = threadIdx.x;

  float m = -3.4e38f;
  for (int i = tid; i < C_DIM; i += 1024) m = fmaxf(m, s[i]);
  m = bmax(m, red);

  float z = 0.f, sw = 0.f;
  for (int i = tid; i < C_DIM; i += 1024) {
    float t = s[i] - m;
    float e = __expf(t);
    z += e;
    sw += e * t;
  }
  z = bsum(z, red);
  sw = bsum(sw, red);
  float H2 = logf(z) - sw / z;

  float h = 0.f;
  for (int i = tid; i < C_DIM; i += 1024) {
    float zi = Z[i];
    h += logf(zi) - S[i] / zi;
  }
  h = bsum(h, red);

  if (tid == 0) out[0] = h / (float)C_DIM + H2;
}

extern "C" void kernel_launch(void* const* d_in, const int* in_sizes, int n_in,
                              void* d_out, int out_size, void* d_ws, size_t ws_size,
                              hipStream_t stream) {
  const float* P = (const float*)d_in[0];
  float* out = (float*)d_out;

  char* ws = (char*)d_ws;
  unsigned* Pb = (unsigned*)ws;                               // 8 MB (bf16)
  float* q = (float*)(ws + (size_t)8 * 1024 * 1024);          // 2 KB
  float* Z = (float*)(ws + (size_t)8 * 1024 * 1024 + 2048);   // 32 KB
  float* S = (float*)(ws + (size_t)8 * 1024 * 1024 + 2048 + 32768);
  float* s = (float*)(ws + (size_t)8 * 1024 * 1024 + 2048 + 65536);

  hipMemsetAsync(q, 0, 2048 + 65536, stream);  // zero q, Z, S

  norm_kernel<<<C_DIM / 4, 256, 0, stream>>>(P, Pb);
  qsum_kernel<<<C_DIM / 128, 256, 0, stream>>>((const unsigned short*)Pb, q);
  ssum_kernel<<<C_DIM / 4, 256, 0, stream>>>((const unsigned short*)Pb, q, s);
  gram_kernel<<<2080, 256, 0, stream>>>((const unsigned short*)Pb, Z, S);
  final_kernel<<<1, 1024, 0, stream>>>(s, Z, S, out);
}

// Round 4
// 144.027 us; speedup vs baseline: 1.2056x; 1.2056x over previous
//
#include <hip/hip_runtime.h>
#include <hip/hip_bf16.h>

#define C_DIM 8192
#define E_DIM 512

using f32x4 = __attribute__((ext_vector_type(4))) float;
using s16x8 = __attribute__((ext_vector_type(8))) short;

__device__ inline void gload_lds16(const void* g, void* l) {
  __builtin_amdgcn_global_load_lds(
      (const __attribute__((address_space(1))) unsigned*)g,
      (__attribute__((address_space(3))) unsigned*)l, 16, 0, 0);
}

__device__ inline unsigned pack_bf16(float a, float b) {
  unsigned ua = __float_as_uint(a), ub = __float_as_uint(b);
  ua = (ua + 0x7fffu + ((ua >> 16) & 1u)) >> 16;
  ub = (ub + 0x7fffu + ((ub >> 16) & 1u)) >> 16;
  return ua | (ub << 16);
}

__device__ inline float bf2f(unsigned short u) {
  return __uint_as_float(((unsigned)u) << 16);
}

// ---------------- Kernel 1: row L2 normalize -> bf16 only -------------------
__global__ __launch_bounds__(256) void norm_kernel(
    const float* __restrict__ P, unsigned* __restrict__ Pb) {
  int wid = threadIdx.x >> 6, lane = threadIdx.x & 63;
  int row = blockIdx.x * 4 + wid;
  const float4* src = (const float4*)(P + (size_t)row * E_DIM);
  float4 v0 = src[lane], v1 = src[lane + 64];
  float ss = v0.x * v0.x + v0.y * v0.y + v0.z * v0.z + v0.w * v0.w +
             v1.x * v1.x + v1.y * v1.y + v1.z * v1.z + v1.w * v1.w;
  for (int m = 32; m; m >>= 1) ss += __shfl_xor(ss, m);
  float inv = 1.0f / fmaxf(sqrtf(ss), 1e-12f);
  v0.x *= inv; v0.y *= inv; v0.z *= inv; v0.w *= inv;
  v1.x *= inv; v1.y *= inv; v1.z *= inv; v1.w *= inv;
  uint2* bd = (uint2*)(Pb + (size_t)row * (E_DIM / 2));
  uint2 b0, b1;
  b0.x = pack_bf16(v0.x, v0.y); b0.y = pack_bf16(v0.z, v0.w);
  b1.x = pack_bf16(v1.x, v1.y); b1.y = pack_bf16(v1.z, v1.w);
  bd[lane] = b0; bd[lane + 64] = b1;
}

// ---------------- Kernel 2: q = column sums of Pb (bf16) --------------------
__global__ __launch_bounds__(256) void qsum_kernel(
    const unsigned short* __restrict__ Pb, float* __restrict__ q) {
  __shared__ float red[4][512];
  int wid = threadIdx.x >> 6, lane = threadIdx.x & 63;
  float a[8];
#pragma unroll
  for (int k = 0; k < 8; ++k) a[k] = 0.f;
  for (int i = 0; i < 32; ++i) {
    int row = blockIdx.x * 128 + wid * 32 + i;
    uint4 v = *(const uint4*)(Pb + (size_t)row * E_DIM + lane * 8);
    a[0] += bf2f((unsigned short)(v.x & 0xffff));
    a[1] += bf2f((unsigned short)(v.x >> 16));
    a[2] += bf2f((unsigned short)(v.y & 0xffff));
    a[3] += bf2f((unsigned short)(v.y >> 16));
    a[4] += bf2f((unsigned short)(v.z & 0xffff));
    a[5] += bf2f((unsigned short)(v.z >> 16));
    a[6] += bf2f((unsigned short)(v.w & 0xffff));
    a[7] += bf2f((unsigned short)(v.w >> 16));
  }
#pragma unroll
  for (int k = 0; k < 8; ++k) red[wid][lane * 8 + k] = a[k];
  __syncthreads();
  for (int c = threadIdx.x; c < 512; c += 256) {
    float t = red[0][c] + red[1][c] + red[2][c] + red[3][c];
    atomicAdd(&q[c], t);
  }
}

// ---------------- Kernel 3: s_j = dot(Pb[j], q) -----------------------------
__global__ __launch_bounds__(256) void ssum_kernel(
    const unsigned short* __restrict__ Pb, const float* __restrict__ q,
    float* __restrict__ s) {
  int wid = threadIdx.x >> 6, lane = threadIdx.x & 63;
  int row = blockIdx.x * 4 + wid;
  uint4 v = *(const uint4*)(Pb + (size_t)row * E_DIM + lane * 8);
  const float4* qv = (const float4*)q;
  float4 q0 = qv[lane * 2], q1 = qv[lane * 2 + 1];
  float d = bf2f((unsigned short)(v.x & 0xffff)) * q0.x +
            bf2f((unsigned short)(v.x >> 16)) * q0.y +
            bf2f((unsigned short)(v.y & 0xffff)) * q0.z +
            bf2f((unsigned short)(v.y >> 16)) * q0.w +
            bf2f((unsigned short)(v.z & 0xffff)) * q1.x +
            bf2f((unsigned short)(v.z >> 16)) * q1.y +
            bf2f((unsigned short)(v.w & 0xffff)) * q1.z +
            bf2f((unsigned short)(v.w >> 16)) * q1.w;
  for (int m = 32; m; m >>= 1) d += __shfl_xor(d, m);
  if (lane == 0) s[row] = d;
}

// ---------------- Kernel 4: fused Gram + exp-entropy partials ---------------
// 256x256 upper-triangle tiles (32x32 grid -> 528 blocks), 8 waves (2Mx4N),
// per-wave 128x64 output, BK=64, double-buffered 2-phase:
//   RD(kk0) -> MFMA(kk0) -> RD(kk1) -> STAGE(next) -> MFMA(kk1) -> barrier
// STAGE sits before a register-only MFMA cluster so the compiler's vmcnt(0)
// drain lands at the barrier, after ~600cy of MFMA cover.
__global__ __launch_bounds__(512, 2) void gram_kernel(
    const unsigned short* __restrict__ Pb, float* __restrict__ Z, float* __restrict__ S) {
  __shared__ unsigned short As[2 * 256 * 64];  // 64 KB
  __shared__ unsigned short Bs[2 * 256 * 64];  // 64 KB

  // XCD-aware remap (528 = 8 * 66, bijective), then triangular decode (NB=32)
  int i0 = blockIdx.x;
  int i = (i0 & 7) * 66 + (i0 >> 3);
  float bi = 32.5f - sqrtf(32.5f * 32.5f - 2.0f * (float)i);
  int by = (int)bi;
  if (by < 0) by = 0;
  while (32 * (by + 1) - ((by + 1) * by) / 2 <= i) ++by;
  while (32 * by - (by * (by - 1)) / 2 > i) --by;
  int bx = by + (i - (32 * by - (by * (by - 1)) / 2));
  bool diag = (bx == by);

  int tid = threadIdx.x, wid = tid >> 6, lane = tid & 63;
  int wr = wid >> 2, wc = wid & 3;  // 2 x 4 wave grid
  int l15 = lane & 15, lh = lane >> 4;

  f32x4 acc[8][4];
#pragma unroll
  for (int m = 0; m < 8; ++m)
#pragma unroll
    for (int n = 0; n < 4; ++n)
      acc[m][n] = (f32x4){0.f, 0.f, 0.f, 0.f};

  int rs = lane >> 3;               // row within 8-row chunk
  int ksw = ((lane & 7) ^ rs) * 8;  // pre-swizzled col group (XOR involution)
  const unsigned short* arow = Pb + (size_t)(by * 256) * E_DIM;
  const unsigned short* brow = Pb + (size_t)(bx * 256) * E_DIM;

#define STAGE(buf, kt)                                                        \
  {                                                                           \
    _Pragma("unroll") for (int j = 0; j < 4; ++j) {                           \
      int ci = wid * 4 + j; /* 32 chunks of 8 rows */                         \
      int r = ci * 8 + rs;                                                    \
      int k = (kt) * 64 + ksw;                                                \
      gload_lds16(arow + (size_t)r * E_DIM + k,                               \
                  (char*)As + (buf) * 32768 + ci * 1024);                     \
      gload_lds16(brow + (size_t)r * E_DIM + k,                               \
                  (char*)Bs + (buf) * 32768 + ci * 1024);                     \
    }                                                                         \
  }

  STAGE(0, 0);
  __syncthreads();

  int cur = 0;
#pragma unroll
  for (int kt = 0; kt < 8; ++kt) {
    s16x8 af[8], bfr[4];
    // ---- kk = 0: read + MFMA ----
#pragma unroll
    for (int m = 0; m < 8; ++m) {
      int row = wr * 128 + m * 16 + l15;
      int slot = lh ^ (l15 & 7);
      af[m] = *(const s16x8*)(As + cur * 16384 + row * 64 + slot * 8);
    }
#pragma unroll
    for (int n = 0; n < 4; ++n) {
      int row = wc * 64 + n * 16 + l15;
      int slot = lh ^ (l15 & 7);
      bfr[n] = *(const s16x8*)(Bs + cur * 16384 + row * 64 + slot * 8);
    }
    __builtin_amdgcn_s_setprio(1);
#pragma unroll
    for (int m = 0; m < 8; ++m)
#pragma unroll
      for (int n = 0; n < 4; ++n)
        acc[m][n] = __builtin_amdgcn_mfma_f32_16x16x32_bf16(
            af[m], bfr[n], acc[m][n], 0, 0, 0);
    __builtin_amdgcn_s_setprio(0);

    // ---- kk = 1: read, then issue next-tile stage, then MFMA ----
    s16x8 af1[8], bfr1[4];
#pragma unroll
    for (int m = 0; m < 8; ++m) {
      int row = wr * 128 + m * 16 + l15;
      int slot = (4 + lh) ^ (l15 & 7);
      af1[m] = *(const s16x8*)(As + cur * 16384 + row * 64 + slot * 8);
    }
#pragma unroll
    for (int n = 0; n < 4; ++n) {
      int row = wc * 64 + n * 16 + l15;
      int slot = (4 + lh) ^ (l15 & 7);
      bfr1[n] = *(const s16x8*)(Bs + cur * 16384 + row * 64 + slot * 8);
    }
    if (kt < 7) STAGE(cur ^ 1, kt + 1);
    __builtin_amdgcn_s_setprio(1);
#pragma unroll
    for (int m = 0; m < 8; ++m)
#pragma unroll
      for (int n = 0; n < 4; ++n)
        acc[m][n] = __builtin_amdgcn_mfma_f32_16x16x32_bf16(
            af1[m], bfr1[n], acc[m][n], 0, 0, 0);
    __builtin_amdgcn_s_setprio(0);

    if (kt < 7) {
      __syncthreads();  // vmcnt+lgkm drain AFTER both MFMA quadrants
      cur ^= 1;
    }
  }
#undef STAGE

  // epilogue: row partials (reduce over l15) + col partials (reduce over lh)
  int rowbase = by * 256 + wr * 128;
  int colbase = bx * 256 + wc * 64;
  float zc[4], sc[4];
#pragma unroll
  for (int n = 0; n < 4; ++n) { zc[n] = 0.f; sc[n] = 0.f; }

#pragma unroll
  for (int m = 0; m < 8; ++m) {
#pragma unroll
    for (int reg = 0; reg < 4; ++reg) {
      float z = 0.f, s = 0.f;
#pragma unroll
      for (int n = 0; n < 4; ++n) {
        float g = acc[m][n][reg];
        float e = __expf(g);
        z += e;
        s += e * g;
        zc[n] += e;
        sc[n] += e * g;
      }
      for (int msk = 8; msk; msk >>= 1) {
        z += __shfl_xor(z, msk);
        s += __shfl_xor(s, msk);
      }
      if (l15 == 0) {
        int grow = rowbase + m * 16 + lh * 4 + reg;
        atomicAdd(&Z[grow], z);
        atomicAdd(&S[grow], s);
      }
    }
  }
  if (!diag) {
#pragma unroll
    for (int n = 0; n < 4; ++n) {
      float z = zc[n], s = sc[n];
      z += __shfl_xor(z, 16); s += __shfl_xor(s, 16);
      z += __shfl_xor(z, 32); s += __shfl_xor(s, 32);
      if (lh == 0) {
        int gcol = colbase + n * 16 + l15;
        atomicAdd(&Z[gcol], z);
        atomicAdd(&S[gcol], s);
      }
    }
  }
}

// ---------------- Kernel 5: finalize ----------------------------------------
__device__ inline float bsum(float v, volatile float* red) {
  int lane = threadIdx.x & 63, wid = threadIdx.x >> 6;
  for (int k = 32; k; k >>= 1) v += __shfl_xor(v, k);
  __syncthreads();
  if (lane == 0) red[wid] = v;
  __syncthreads();
  float r = 0.f;
  if (wid == 0) {
    r = (lane < 16) ? red[lane] : 0.f;
    for (int k = 8; k; k >>= 1) r += __shfl_xor(r, k);
  }
  if (threadIdx.x == 0) red[16] = r;
  __syncthreads();
  return red[16];
}

__device__ inline float bmax(float v, volatile float* red) {
  int lane = threadIdx.x & 63, wid = threadIdx.x >> 6;
  for (int k = 32; k; k >>= 1) v = fmaxf(v, __shfl_xor(v, k));
  __syncthreads();
  if (lane == 0) red[wid] = v;
  __syncthreads();
  float r = -3.4e38f;
  if (wid == 0) {
    r = (lane < 16) ? red[lane] : -3.4e38f;
    for (int k = 8; k; k >>= 1) r = fmaxf(r, __shfl_xor(r, k));
  }
  if (threadIdx.x == 0) red[16] = r;
  __syncthreads();
  return red[16];
}

__global__ __launch_bounds__(1024) void final_kernel(
    const float* __restrict__ s, const float* __restrict__ Z,
    const float* __restrict__ S, float* __restrict__ out) {
  __shared__ float red[17];
  int tid = threadIdx.x;

  float m = -3.4e38f;
  for (int i = tid; i < C_DIM; i += 1024) m = fmaxf(m, s[i]);
  m = bmax(m, red);

  float z = 0.f, sw = 0.f;
  for (int i = tid; i < C_DIM; i += 1024) {
    float t = s[i] - m;
    float e = __expf(t);
    z += e;
    sw += e * t;
  }
  z = bsum(z, red);
  sw = bsum(sw, red);
  float H2 = logf(z) - sw / z;

  float h = 0.f;
  for (int i = tid; i < C_DIM; i += 1024) {
    float zi = Z[i];
    h += logf(zi) - S[i] / zi;
  }
  h = bsum(h, red);

  if (tid == 0) out[0] = h / (float)C_DIM + H2;
}

extern "C" void kernel_launch(void* const* d_in, const int* in_sizes, int n_in,
                              void* d_out, int out_size, void* d_ws, size_t ws_size,
                              hipStream_t stream) {
  const float* P = (const float*)d_in[0];
  float* out = (float*)d_out;

  char* ws = (char*)d_ws;
  unsigned* Pb = (unsigned*)ws;                               // 8 MB (bf16)
  float* q = (float*)(ws + (size_t)8 * 1024 * 1024);          // 2 KB
  float* Z = (float*)(ws + (size_t)8 * 1024 * 1024 + 2048);   // 32 KB
  float* S = (float*)(ws + (size_t)8 * 1024 * 1024 + 2048 + 32768);
  float* s = (float*)(ws + (size_t)8 * 1024 * 1024 + 2048 + 65536);

  hipMemsetAsync(q, 0, 2048 + 65536, stream);  // zero q, Z, S

  norm_kernel<<<C_DIM / 4, 256, 0, stream>>>(P, Pb);
  qsum_kernel<<<C_DIM / 128, 256, 0, stream>>>((const unsigned short*)Pb, q);
  ssum_kernel<<<C_DIM / 4, 256, 0, stream>>>((const unsigned short*)Pb, q, s);
  gram_kernel<<<528, 512, 0, stream>>>((const unsigned short*)Pb, Z, S);
  final_kernel<<<1, 1024, 0, stream>>>(s, Z, S, out);
}

// Round 5
// 99.729 us; speedup vs baseline: 1.7412x; 1.4442x over previous
//
#include <hip/hip_runtime.h>
#include <hip/hip_bf16.h>

#define C_DIM 8192
#define E_DIM 512

using f32x4 = __attribute__((ext_vector_type(4))) float;
using s16x8 = __attribute__((ext_vector_type(8))) short;

__device__ inline void gload_lds16(const void* g, void* l) {
  __builtin_amdgcn_global_load_lds(
      (const __attribute__((address_space(1))) unsigned*)g,
      (__attribute__((address_space(3))) unsigned*)l, 16, 0, 0);
}

__device__ inline unsigned pack_bf16(float a, float b) {
  unsigned ua = __float_as_uint(a), ub = __float_as_uint(b);
  ua = (ua + 0x7fffu + ((ua >> 16) & 1u)) >> 16;
  ub = (ub + 0x7fffu + ((ub >> 16) & 1u)) >> 16;
  return ua | (ub << 16);
}

__device__ inline float bf2f(unsigned short u) {
  return __uint_as_float(((unsigned)u) << 16);
}

// ---------------- Kernel 1: row L2 normalize -> bf16 only -------------------
__global__ __launch_bounds__(256) void norm_kernel(
    const float* __restrict__ P, unsigned* __restrict__ Pb) {
  int wid = threadIdx.x >> 6, lane = threadIdx.x & 63;
  int row = blockIdx.x * 4 + wid;
  const float4* src = (const float4*)(P + (size_t)row * E_DIM);
  float4 v0 = src[lane], v1 = src[lane + 64];
  float ss = v0.x * v0.x + v0.y * v0.y + v0.z * v0.z + v0.w * v0.w +
             v1.x * v1.x + v1.y * v1.y + v1.z * v1.z + v1.w * v1.w;
  for (int m = 32; m; m >>= 1) ss += __shfl_xor(ss, m);
  float inv = 1.0f / fmaxf(sqrtf(ss), 1e-12f);
  v0.x *= inv; v0.y *= inv; v0.z *= inv; v0.w *= inv;
  v1.x *= inv; v1.y *= inv; v1.z *= inv; v1.w *= inv;
  uint2* bd = (uint2*)(Pb + (size_t)row * (E_DIM / 2));
  uint2 b0, b1;
  b0.x = pack_bf16(v0.x, v0.y); b0.y = pack_bf16(v0.z, v0.w);
  b1.x = pack_bf16(v1.x, v1.y); b1.y = pack_bf16(v1.z, v1.w);
  bd[lane] = b0; bd[lane + 64] = b1;
}

// ---------------- Kernel 2: q = column sums of Pb (bf16) --------------------
__global__ __launch_bounds__(256) void qsum_kernel(
    const unsigned short* __restrict__ Pb, float* __restrict__ q) {
  __shared__ float red[4][512];
  int wid = threadIdx.x >> 6, lane = threadIdx.x & 63;
  float a[8];
#pragma unroll
  for (int k = 0; k < 8; ++k) a[k] = 0.f;
  for (int i = 0; i < 32; ++i) {
    int row = blockIdx.x * 128 + wid * 32 + i;
    uint4 v = *(const uint4*)(Pb + (size_t)row * E_DIM + lane * 8);
    a[0] += bf2f((unsigned short)(v.x & 0xffff));
    a[1] += bf2f((unsigned short)(v.x >> 16));
    a[2] += bf2f((unsigned short)(v.y & 0xffff));
    a[3] += bf2f((unsigned short)(v.y >> 16));
    a[4] += bf2f((unsigned short)(v.z & 0xffff));
    a[5] += bf2f((unsigned short)(v.z >> 16));
    a[6] += bf2f((unsigned short)(v.w & 0xffff));
    a[7] += bf2f((unsigned short)(v.w >> 16));
  }
#pragma unroll
  for (int k = 0; k < 8; ++k) red[wid][lane * 8 + k] = a[k];
  __syncthreads();
  for (int c = threadIdx.x; c < 512; c += 256) {
    float t = red[0][c] + red[1][c] + red[2][c] + red[3][c];
    atomicAdd(&q[c], t);
  }
}

// ---------------- Kernel 3: s_j = dot(Pb[j], q) -----------------------------
__global__ __launch_bounds__(256) void ssum_kernel(
    const unsigned short* __restrict__ Pb, const float* __restrict__ q,
    float* __restrict__ s) {
  int wid = threadIdx.x >> 6, lane = threadIdx.x & 63;
  int row = blockIdx.x * 4 + wid;
  uint4 v = *(const uint4*)(Pb + (size_t)row * E_DIM + lane * 8);
  const float4* qv = (const float4*)q;
  float4 q0 = qv[lane * 2], q1 = qv[lane * 2 + 1];
  float d = bf2f((unsigned short)(v.x & 0xffff)) * q0.x +
            bf2f((unsigned short)(v.x >> 16)) * q0.y +
            bf2f((unsigned short)(v.y & 0xffff)) * q0.z +
            bf2f((unsigned short)(v.y >> 16)) * q0.w +
            bf2f((unsigned short)(v.z & 0xffff)) * q1.x +
            bf2f((unsigned short)(v.z >> 16)) * q1.y +
            bf2f((unsigned short)(v.w & 0xffff)) * q1.z +
            bf2f((unsigned short)(v.w >> 16)) * q1.w;
  for (int m = 32; m; m >>= 1) d += __shfl_xor(d, m);
  if (lane == 0) s[row] = d;
}

// ---------------- Kernel 4: fused Gram + exp-entropy partials ---------------
// Exact R2 loop structure (best measured). Epilogue: NO atomics — partials go
// to collision-free private slices Zp/Sp[rb=64][slot=128][rowin=128]:
//   row-partials of tile (by,bx), wave (wr,wc) -> rb=by, slot=2*bx+wc
//   col-partials (mirror, off-diag)            -> rb=bx, slot=2*by+wr
// Every (rb,slot,rowin) written exactly once -> no zero-init, no contention.
__global__ __launch_bounds__(256) void gram_kernel(
    const unsigned short* __restrict__ Pb, float* __restrict__ Zp,
    float* __restrict__ Sp) {
  __shared__ unsigned short As[128 * 64];
  __shared__ unsigned short Bs[128 * 64];

  // triangular decode -> (by, bx), bx >= by
  int i = blockIdx.x;
  float bi = 64.5f - sqrtf(64.5f * 64.5f - 2.0f * (float)i);
  int by = (int)bi;
  if (by < 0) by = 0;
  while (64 * (by + 1) - ((by + 1) * by) / 2 <= i) ++by;
  while (64 * by - (by * (by - 1)) / 2 > i) --by;
  int bx = by + (i - (64 * by - (by * (by - 1)) / 2));
  bool diag = (bx == by);

  int tid = threadIdx.x, wid = tid >> 6, lane = tid & 63;
  int wr = wid >> 1, wc = wid & 1;
  int l15 = lane & 15, lh = lane >> 4;

  f32x4 acc[4][4];
  for (int m = 0; m < 4; ++m)
    for (int n = 0; n < 4; ++n)
      acc[m][n] = (f32x4){0.f, 0.f, 0.f, 0.f};

  int rs = lane >> 3;                 // row within 8-row chunk
  int ksw = ((lane & 7) ^ rs) * 8;    // pre-swizzled col group (XOR involution)

  for (int kt = 0; kt < 8; ++kt) {
#pragma unroll
    for (int j = 0; j < 4; ++j) {
      int ci = wid * 4 + j;
      int r = ci * 8 + rs;
      int k = kt * 64 + ksw;
      gload_lds16(Pb + ((size_t)(by * 128 + r) * E_DIM + k), (char*)As + ci * 1024);
      gload_lds16(Pb + ((size_t)(bx * 128 + r) * E_DIM + k), (char*)Bs + ci * 1024);
    }
    __syncthreads();

    s16x8 af[4][2], bfr[4][2];
#pragma unroll
    for (int m = 0; m < 4; ++m)
#pragma unroll
      for (int kk = 0; kk < 2; ++kk) {
        int row = wr * 64 + m * 16 + l15;
        int slot = (kk * 4 + lh) ^ (l15 & 7);
        af[m][kk] = *(const s16x8*)(As + row * 64 + slot * 8);
      }
#pragma unroll
    for (int n = 0; n < 4; ++n)
#pragma unroll
      for (int kk = 0; kk < 2; ++kk) {
        int row = wc * 64 + n * 16 + l15;
        int slot = (kk * 4 + lh) ^ (l15 & 7);
        bfr[n][kk] = *(const s16x8*)(Bs + row * 64 + slot * 8);
      }

#pragma unroll
    for (int kk = 0; kk < 2; ++kk)
#pragma unroll
      for (int m = 0; m < 4; ++m)
#pragma unroll
        for (int n = 0; n < 4; ++n)
          acc[m][n] = __builtin_amdgcn_mfma_f32_16x16x32_bf16(
              af[m][kk], bfr[n][kk], acc[m][n], 0, 0, 0);
    __syncthreads();
  }

  // epilogue: row partials (reduce over l15) + col partials (reduce over lh)
  float zc[4], sc[4];
#pragma unroll
  for (int n = 0; n < 4; ++n) { zc[n] = 0.f; sc[n] = 0.f; }

  int slotR = bx * 2 + wc;
#pragma unroll
  for (int m = 0; m < 4; ++m) {
#pragma unroll
    for (int reg = 0; reg < 4; ++reg) {
      float z = 0.f, s = 0.f;
#pragma unroll
      for (int n = 0; n < 4; ++n) {
        float g = acc[m][n][reg];
        float e = __expf(g);
        z += e;
        s += e * g;
        zc[n] += e;
        sc[n] += e * g;
      }
      for (int msk = 8; msk; msk >>= 1) {
        z += __shfl_xor(z, msk);
        s += __shfl_xor(s, msk);
      }
      if (l15 == 0) {
        int rowin = wr * 64 + m * 16 + lh * 4 + reg;
        size_t idx = (size_t)by * 16384 + (size_t)slotR * 128 + rowin;
        Zp[idx] = z;
        Sp[idx] = s;
      }
    }
  }
  if (!diag) {
    int slotC = by * 2 + wr;
#pragma unroll
    for (int n = 0; n < 4; ++n) {
      float z = zc[n], s = sc[n];
      z += __shfl_xor(z, 16); s += __shfl_xor(s, 16);
      z += __shfl_xor(z, 32); s += __shfl_xor(s, 32);
      if (lh == 0) {
        int colin = wc * 64 + n * 16 + l15;
        size_t idx = (size_t)bx * 16384 + (size_t)slotC * 128 + colin;
        Zp[idx] = z;
        Sp[idx] = s;
      }
    }
  }
}

// ---------------- Kernel 5: fold 128 slots/row -> per-row entropy -----------
// Block rb: rows rb*128..+128. Threads 0..127 sum Z, 128..255 sum S;
// per slot-iteration the 128 threads read 512 B contiguous (coalesced).
__global__ __launch_bounds__(256) void reduce_kernel(
    const float* __restrict__ Zp, const float* __restrict__ Sp,
    float* __restrict__ Hrow) {
  __shared__ float zbuf[128], sbuf[128];
  int rb = blockIdx.x;
  int t = threadIdx.x;
  int row = t & 127;
  const float* src = (t >= 128) ? Sp : Zp;
  size_t base = (size_t)rb * 16384 + row;
  float acc = 0.f;
#pragma unroll 8
  for (int sl = 0; sl < 128; ++sl) acc += src[base + (size_t)sl * 128];
  if (t >= 128) sbuf[row] = acc; else zbuf[row] = acc;
  __syncthreads();
  if (t < 128) {
    float z = zbuf[t], s2 = sbuf[t];
    Hrow[rb * 128 + t] = logf(z) - s2 / z;
  }
}

// ---------------- Kernel 6: finalize ----------------------------------------
__device__ inline float bsum(float v, volatile float* red) {
  int lane = threadIdx.x & 63, wid = threadIdx.x >> 6;
  for (int k = 32; k; k >>= 1) v += __shfl_xor(v, k);
  __syncthreads();
  if (lane == 0) red[wid] = v;
  __syncthreads();
  float r = 0.f;
  if (wid == 0) {
    r = (lane < 16) ? red[lane] : 0.f;
    for (int k = 8; k; k >>= 1) r += __shfl_xor(r, k);
  }
  if (threadIdx.x == 0) red[16] = r;
  __syncthreads();
  return red[16];
}

__device__ inline float bmax(float v, volatile float* red) {
  int lane = threadIdx.x & 63, wid = threadIdx.x >> 6;
  for (int k = 32; k; k >>= 1) v = fmaxf(v, __shfl_xor(v, k));
  __syncthreads();
  if (lane == 0) red[wid] = v;
  __syncthreads();
  float r = -3.4e38f;
  if (wid == 0) {
    r = (lane < 16) ? red[lane] : -3.4e38f;
    for (int k = 8; k; k >>= 1) r = fmaxf(r, __shfl_xor(r, k));
  }
  if (threadIdx.x == 0) red[16] = r;
  __syncthreads();
  return red[16];
}

__global__ __launch_bounds__(1024) void final_kernel(
    const float* __restrict__ s, const float* __restrict__ Hrow,
    float* __restrict__ out) {
  __shared__ float red[17];
  int tid = threadIdx.x;

  float m = -3.4e38f;
  for (int i = tid; i < C_DIM; i += 1024) m = fmaxf(m, s[i]);
  m = bmax(m, red);

  float z = 0.f, sw = 0.f;
  for (int i = tid; i < C_DIM; i += 1024) {
    float t = s[i] - m;
    float e = __expf(t);
    z += e;
    sw += e * t;
  }
  z = bsum(z, red);
  sw = bsum(sw, red);
  float H2 = logf(z) - sw / z;

  float h = 0.f;
  for (int i = tid; i < C_DIM; i += 1024) h += Hrow[i];
  h = bsum(h, red);

  if (tid == 0) out[0] = h / (float)C_DIM + H2;
}

extern "C" void kernel_launch(void* const* d_in, const int* in_sizes, int n_in,
                              void* d_out, int out_size, void* d_ws, size_t ws_size,
                              hipStream_t stream) {
  const float* P = (const float*)d_in[0];
  float* out = (float*)d_out;

  char* ws = (char*)d_ws;
  unsigned* Pb = (unsigned*)ws;                                   // 8 MB (bf16)
  float* Zp = (float*)(ws + ((size_t)8 << 20));                   // 4 MB
  float* Sp = (float*)(ws + ((size_t)12 << 20));                  // 4 MB
  float* q = (float*)(ws + ((size_t)16 << 20));                   // 2 KB
  float* s = (float*)(ws + ((size_t)16 << 20) + 4096);            // 32 KB
  float* Hrow = (float*)(ws + ((size_t)16 << 20) + 4096 + 32768); // 32 KB

  hipMemsetAsync(q, 0, 2048, stream);  // only q needs zeroing

  norm_kernel<<<C_DIM / 4, 256, 0, stream>>>(P, Pb);
  qsum_kernel<<<C_DIM / 128, 256, 0, stream>>>((const unsigned short*)Pb, q);
  ssum_kernel<<<C_DIM / 4, 256, 0, stream>>>((const unsigned short*)Pb, q, s);
  gram_kernel<<<2080, 256, 0, stream>>>((const unsigned short*)Pb, Zp, Sp);
  reduce_kernel<<<64, 256, 0, stream>>>(Zp, Sp, Hrow);
  final_kernel<<<1, 1024, 0, stream>>>(s, Hrow, out);
}